// Round 11
// baseline (1362.172 us; speedup 1.0000x reference)
//
#include <hip/hip_runtime.h>
#include <math.h>
#include <stdint.h>

// 2-layer GCN anomaly scorer — binned counting-sort + LDS accumulation.
// R4: device atomics write through HBM -> 984us. R5: binned LDS 358us.
// R6: split4 -> 315us. R7: 2-level scan -> 160us. R8: split8 + u64 packed
// LDS atomics -> 115us. R9: EBC=256 + XCD swizzle + exact i64 -> 105us.
// R10: uint4-vectorized sweeps + padded bins -> 97us. R11: collapse 11
// dispatches -> 7: scan2K absorbs gapK; deg/agg/out use last-block-merge
// (partial + __threadfence + per-bin done counter; last arriver merges).
//
// Math: agg[d] = dinv[d]*(sum_{s->d} y[s] + y[d]),  y = dinv.*x
//       g      = dinv .* (relu(agg@W1+b1)@W2)
//       out[d] = sigmoid(dinv[d]*(sum_{s->d} g[s] + g[d]) + b2)
// Fixed-point: q(v) = rn((v+16)*2^21); fields (f0,f1),(f2,f3) in two u64s.

#define BINBITS 8
#define BINSZ   256
#define NBMAX   512
#define EBC     256      // edge-chunk blocks for count/fill
#define THR     256
#define QS      2097152.0f   // 2^21
#define SENT    0xFFFFFFFFu

__device__ __forceinline__ uint32_t packq(float v) {
    return __float2uint_rn(fmaf(v, QS, 16.0f * QS));
}

// ---------------- sort phase ----------------

__global__ void countK(const int* __restrict__ dst, uint32_t* __restrict__ bc,
                       uint32_t* __restrict__ counters, int e, int nb) {
    __shared__ uint32_t cnt[NBMAX];
    int t = threadIdx.x, b = blockIdx.x;
    if (b == 0) {                       // zero the 3 per-bin done-counter arrays
        for (int i = t; i < 3 * nb; i += THR) counters[i] = 0u;
    }
    for (int i = t; i < nb; i += THR) cnt[i] = 0;
    __syncthreads();
    int epb = (e + EBC - 1) / EBC;
    int lo = b * epb, hi = min(e, lo + epb);
    if (((lo | hi) & 3) == 0 && (((uintptr_t)dst & 15) == 0)) {
        const int4* dst4 = (const int4*)dst;
        for (int i = lo / 4 + t; i < hi / 4; i += THR) {
            int4 v = dst4[i];
            atomicAdd(&cnt[((unsigned)v.x) >> BINBITS], 1u);
            atomicAdd(&cnt[((unsigned)v.y) >> BINBITS], 1u);
            atomicAdd(&cnt[((unsigned)v.z) >> BINBITS], 1u);
            atomicAdd(&cnt[((unsigned)v.w) >> BINBITS], 1u);
        }
    } else {
        for (int i = lo + t; i < hi; i += THR)
            atomicAdd(&cnt[((unsigned)dst[i]) >> BINBITS], 1u);
    }
    __syncthreads();
    for (int i = t; i < nb; i += THR) bc[(size_t)i * EBC + b] = cnt[i];
}

// per-bin exclusive scan of the EBC per-block counts (block == EBC threads)
__global__ void scan1K(uint32_t* __restrict__ bc, uint32_t* __restrict__ binSum) {
    __shared__ uint32_t s[EBC];
    int t = threadIdx.x, bin = blockIdx.x;
    uint32_t v = bc[(size_t)bin * EBC + t];
    s[t] = v;
    __syncthreads();
    for (int off = 1; off < EBC; off <<= 1) {
        uint32_t u = (t >= off) ? s[t - off] : 0u;
        __syncthreads();
        s[t] += u;
        __syncthreads();
    }
    bc[(size_t)bin * EBC + t] = s[t] - v;           // exclusive
    if (t == EBC - 1) binSum[bin] = s[t];
}

// padded (multiple-of-4) exclusive scan of bin sums -> binStart; also writes
// the <=3 sentinel pad slots per bin directly (absorbs R10's gapK).
__global__ void scan2K(const uint32_t* __restrict__ binSum,
                       uint32_t* __restrict__ binStart,
                       uint32_t* __restrict__ records, int nb) {
    __shared__ uint32_t s[512];
    int t = threadIdx.x;
    uint32_t real = (t < nb) ? binSum[t] : 0u;
    uint32_t v = (real + 3u) & ~3u;
    s[t] = v;
    __syncthreads();
    for (int off = 1; off < 512; off <<= 1) {
        uint32_t u = (t >= off) ? s[t - off] : 0u;
        __syncthreads();
        s[t] += u;
        __syncthreads();
    }
    if (t < nb) {
        uint32_t start = s[t] - v;
        binStart[t] = start;
        for (uint32_t q = start + real; q < start + v; ++q) records[q] = SENT;
    }
    if (t == nb - 1) binStart[nb] = s[t];           // padded total
}

__global__ void fillK(const int* __restrict__ src, const int* __restrict__ dst,
                      const uint32_t* __restrict__ bc,
                      const uint32_t* __restrict__ binStart,
                      uint32_t* __restrict__ records, int e, int nb) {
    __shared__ uint32_t cur[NBMAX];
    int t = threadIdx.x;
    // XCD-contiguous chunk swizzle (R9): same-XCD blocks take contiguous
    // edge chunks so shared record lines stay in one XCD's L2.
    int b = (blockIdx.x & 7) * (EBC / 8) + (blockIdx.x >> 3);
    for (int i = t; i < nb; i += THR)
        cur[i] = bc[(size_t)i * EBC + b] + binStart[i];
    __syncthreads();
    int epb = (e + EBC - 1) / EBC;
    int lo = b * epb, hi = min(e, lo + epb);
    if (((lo | hi) & 3) == 0 && (((uintptr_t)src & 15) == 0) && (((uintptr_t)dst & 15) == 0)) {
        const int4* src4 = (const int4*)src;
        const int4* dst4 = (const int4*)dst;
        for (int i = lo / 4 + t; i < hi / 4; i += THR) {
            int4 dv = dst4[i];
            int4 sv = src4[i];
            unsigned d0 = (unsigned)dv.x, d1 = (unsigned)dv.y;
            unsigned d2 = (unsigned)dv.z, d3 = (unsigned)dv.w;
            uint32_t p0 = atomicAdd(&cur[d0 >> BINBITS], 1u);
            records[p0] = (((unsigned)sv.x) << BINBITS) | (d0 & (BINSZ - 1));
            uint32_t p1 = atomicAdd(&cur[d1 >> BINBITS], 1u);
            records[p1] = (((unsigned)sv.y) << BINBITS) | (d1 & (BINSZ - 1));
            uint32_t p2 = atomicAdd(&cur[d2 >> BINBITS], 1u);
            records[p2] = (((unsigned)sv.z) << BINBITS) | (d2 & (BINSZ - 1));
            uint32_t p3 = atomicAdd(&cur[d3 >> BINBITS], 1u);
            records[p3] = (((unsigned)sv.w) << BINBITS) | (d3 & (BINSZ - 1));
        }
    } else {
        for (int i = lo + t; i < hi; i += THR) {
            unsigned d = (unsigned)dst[i];
            unsigned s = (unsigned)src[i];
            uint32_t slot = atomicAdd(&cur[d >> BINBITS], 1u);
            records[slot] = (s << BINBITS) | (d & (BINSZ - 1));
        }
    }
}

// ---------------- degree + dinv + packed y (last-block merges) ----------------

__global__ void degY(const uint32_t* __restrict__ records,
                     const uint32_t* __restrict__ binStart,
                     const float4* __restrict__ x4,
                     uint32_t* __restrict__ histP,
                     float* __restrict__ dinv, uint32_t* __restrict__ deg,
                     ulonglong2* __restrict__ y4q,
                     uint32_t* __restrict__ cnt, int split, int n) {
    __shared__ uint32_t hist[BINSZ];
    __shared__ uint32_t done;
    int t = threadIdx.x;
    int bin = blockIdx.x / split, sub = blockIdx.x % split;
    hist[t] = 0u;
    __syncthreads();
    uint32_t lo = binStart[bin], hi = binStart[bin + 1];
    uint32_t chunk = (((hi - lo + split - 1) / split) + 3u) & ~3u;
    uint32_t slo = lo + sub * chunk;
    uint32_t shi = min(hi, slo + chunk);
    const uint4* rec4 = (const uint4*)records;
    for (uint32_t i = slo / 4 + t; i < shi / 4; i += THR) {
        uint4 r = rec4[i];
        if (r.x != SENT) atomicAdd(&hist[r.x & (BINSZ - 1)], 1u);
        if (r.y != SENT) atomicAdd(&hist[r.y & (BINSZ - 1)], 1u);
        if (r.z != SENT) atomicAdd(&hist[r.z & (BINSZ - 1)], 1u);
        if (r.w != SENT) atomicAdd(&hist[r.w & (BINSZ - 1)], 1u);
    }
    __syncthreads();
    histP[(size_t)blockIdx.x * BINSZ + t] = hist[t];
    __threadfence();
    if (t == 0) done = atomicAdd(&cnt[bin], 1u);
    __syncthreads();
    if (done != (uint32_t)(split - 1)) return;      // not the last sub-block
    __threadfence();
    uint32_t c = 0;
    size_t base = (size_t)bin * split * BINSZ;
    for (int s2 = 0; s2 < split; ++s2) c += histP[base + (size_t)s2 * BINSZ + t];
    int node = (bin << BINBITS) + t;
    if (node >= n) return;
    float dd = rsqrtf(1.0f + (float)c);
    dinv[node] = dd;
    deg[node] = c;
    float4 xv = x4[node];
    uint32_t q0 = packq(dd * xv.x), q1 = packq(dd * xv.y);
    uint32_t q2 = packq(dd * xv.z), q3 = packq(dd * xv.w);
    ulonglong2 p;
    p.x = ((unsigned long long)q1 << 32) | q0;
    p.y = ((unsigned long long)q3 << 32) | q2;
    y4q[node] = p;
}

// ---------------- layer-1 aggregation + transform (last-block merges) ----------

__global__ void aggT(const uint32_t* __restrict__ records,
                     const uint32_t* __restrict__ binStart,
                     const ulonglong2* __restrict__ y4q,
                     unsigned long long* __restrict__ aggP,
                     const float* __restrict__ dinv, const uint32_t* __restrict__ deg,
                     const float4* __restrict__ x4,
                     const float* __restrict__ W1, const float* __restrict__ b1,
                     const float* __restrict__ W2,
                     float* __restrict__ g,
                     uint32_t* __restrict__ cnt, int split, int n) {
    __shared__ unsigned long long acc[2 * BINSZ];
    __shared__ uint32_t done;
    int t = threadIdx.x;
    int bin = blockIdx.x / split, sub = blockIdx.x % split;
    acc[t] = 0ull;
    acc[BINSZ + t] = 0ull;
    __syncthreads();
    uint32_t lo = binStart[bin], hi = binStart[bin + 1];
    uint32_t chunk = (((hi - lo + split - 1) / split) + 3u) & ~3u;
    uint32_t slo = lo + sub * chunk;
    uint32_t shi = min(hi, slo + chunk);
    const uint4* rec4 = (const uint4*)records;
    for (uint32_t i = slo / 4 + t; i < shi / 4; i += THR) {
        uint4 r = rec4[i];
        unsigned s0 = (r.x == SENT) ? 0u : (r.x >> BINBITS);
        unsigned s1 = (r.y == SENT) ? 0u : (r.y >> BINBITS);
        unsigned s2 = (r.z == SENT) ? 0u : (r.z >> BINBITS);
        unsigned s3 = (r.w == SENT) ? 0u : (r.w >> BINBITS);
        ulonglong2 y0 = y4q[s0];
        ulonglong2 y1 = y4q[s1];
        ulonglong2 y2 = y4q[s2];
        ulonglong2 y3 = y4q[s3];
        if (r.x != SENT) { unsigned d = r.x & (BINSZ - 1); atomicAdd(&acc[d], y0.x); atomicAdd(&acc[BINSZ + d], y0.y); }
        if (r.y != SENT) { unsigned d = r.y & (BINSZ - 1); atomicAdd(&acc[d], y1.x); atomicAdd(&acc[BINSZ + d], y1.y); }
        if (r.z != SENT) { unsigned d = r.z & (BINSZ - 1); atomicAdd(&acc[d], y2.x); atomicAdd(&acc[BINSZ + d], y2.y); }
        if (r.w != SENT) { unsigned d = r.w & (BINSZ - 1); atomicAdd(&acc[d], y3.x); atomicAdd(&acc[BINSZ + d], y3.y); }
    }
    __syncthreads();
    unsigned long long* p = aggP + (size_t)blockIdx.x * (2 * BINSZ);
    p[t] = acc[t];
    p[BINSZ + t] = acc[BINSZ + t];
    __threadfence();
    if (t == 0) done = atomicAdd(&cnt[bin], 1u);
    __syncthreads();
    if (done != (uint32_t)(split - 1)) return;
    __threadfence();
    __shared__ float sW1[128], sb1[32], sW2[32];
    if (t < 128) sW1[t] = W1[t];
    else if (t < 160) sb1[t - 128] = b1[t - 128];
    else if (t < 192) sW2[t - 160] = W2[t - 160];
    __syncthreads();
    int node = (bin << BINBITS) + t;
    if (node >= n) return;
    unsigned long long s0lo = 0, s0hi = 0, s1lo = 0, s1hi = 0;
    size_t base = (size_t)bin * split * (2 * BINSZ);
    for (int s2 = 0; s2 < split; ++s2) {
        const unsigned long long* q = aggP + base + (size_t)s2 * (2 * BINSZ);
        unsigned long long P0 = q[t], P1 = q[BINSZ + t];
        s0lo += (uint32_t)P0; s0hi += (uint32_t)(P0 >> 32);
        s1lo += (uint32_t)P1; s1hi += (uint32_t)(P1 >> 32);
    }
    // exact de-bias + conversion (R9): split at 2^21 so both halves are exact.
    long long bias = (long long)deg[node] << 25;   // deg * 16 * 2^21
    const float inv = 1.0f / QS;
    long long v0 = (long long)s0lo - bias, v1 = (long long)s0hi - bias;
    long long v2 = (long long)s1lo - bias, v3 = (long long)s1hi - bias;
    float T0 = (float)(v0 >> 21) + (float)(v0 & 0x1FFFFF) * inv;
    float T1 = (float)(v1 >> 21) + (float)(v1 & 0x1FFFFF) * inv;
    float T2 = (float)(v2 >> 21) + (float)(v2 & 0x1FFFFF) * inv;
    float T3 = (float)(v3 >> 21) + (float)(v3 & 0x1FFFFF) * inv;
    float dd = dinv[node];
    float4 xv = x4[node];
    float a0 = dd * (T0 + dd * xv.x), a1 = dd * (T1 + dd * xv.y);
    float a2 = dd * (T2 + dd * xv.z), a3 = dd * (T3 + dd * xv.w);
    float hv = 0.f;
#pragma unroll
    for (int j = 0; j < 32; ++j) {
        float o = fmaf(a0, sW1[j], fmaf(a1, sW1[32 + j],
                  fmaf(a2, sW1[64 + j], fmaf(a3, sW1[96 + j], sb1[j]))));
        hv += fmaxf(o, 0.f) * sW2[j];
    }
    g[node] = dd * hv;
}

// ---------------- layer-2 + sigmoid (last-block merges) ----------------

__global__ void outF(const uint32_t* __restrict__ records,
                     const uint32_t* __restrict__ binStart,
                     const float* __restrict__ g,
                     float* __restrict__ outP,
                     const float* __restrict__ dinv, const float* __restrict__ b2,
                     float* __restrict__ out,
                     uint32_t* __restrict__ cnt, int split, int n) {
    __shared__ float accg[BINSZ];
    __shared__ uint32_t done;
    int t = threadIdx.x;
    int bin = blockIdx.x / split, sub = blockIdx.x % split;
    accg[t] = 0.f;
    __syncthreads();
    uint32_t lo = binStart[bin], hi = binStart[bin + 1];
    uint32_t chunk = (((hi - lo + split - 1) / split) + 3u) & ~3u;
    uint32_t slo = lo + sub * chunk;
    uint32_t shi = min(hi, slo + chunk);
    const uint4* rec4 = (const uint4*)records;
    for (uint32_t i = slo / 4 + t; i < shi / 4; i += THR) {
        uint4 r = rec4[i];
        unsigned s0 = (r.x == SENT) ? 0u : (r.x >> BINBITS);
        unsigned s1 = (r.y == SENT) ? 0u : (r.y >> BINBITS);
        unsigned s2 = (r.z == SENT) ? 0u : (r.z >> BINBITS);
        unsigned s3 = (r.w == SENT) ? 0u : (r.w >> BINBITS);
        float g0 = g[s0], g1 = g[s1], g2 = g[s2], g3 = g[s3];
        if (r.x != SENT) atomicAdd(&accg[r.x & (BINSZ - 1)], g0);
        if (r.y != SENT) atomicAdd(&accg[r.y & (BINSZ - 1)], g1);
        if (r.z != SENT) atomicAdd(&accg[r.z & (BINSZ - 1)], g2);
        if (r.w != SENT) atomicAdd(&accg[r.w & (BINSZ - 1)], g3);
    }
    __syncthreads();
    outP[(size_t)blockIdx.x * BINSZ + t] = accg[t];
    __threadfence();
    if (t == 0) done = atomicAdd(&cnt[bin], 1u);
    __syncthreads();
    if (done != (uint32_t)(split - 1)) return;
    __threadfence();
    int node = (bin << BINBITS) + t;
    if (node >= n) return;
    float s = 0.f;
    size_t base = (size_t)bin * split * BINSZ;
    for (int k = 0; k < split; ++k)
        s += outP[base + (size_t)k * BINSZ + t];
    float v = dinv[node] * (s + g[node]) + b2[0];
    out[node] = 1.0f / (1.0f + expf(-v));
}

// ---------------- launcher ----------------

extern "C" void kernel_launch(void* const* d_in, const int* in_sizes, int n_in,
                              void* d_out, int out_size, void* d_ws, size_t ws_size,
                              hipStream_t stream) {
    const float* x  = (const float*)d_in[0];
    const int*   ei = (const int*)d_in[1];
    const float* W1 = (const float*)d_in[2];
    const float* b1 = (const float*)d_in[3];
    const float* W2 = (const float*)d_in[4];
    const float* b2 = (const float*)d_in[5];
    float* out = (float*)d_out;

    const int n = in_sizes[0] / 4;            // 100000
    const int e = in_sizes[1] / 2;            // 3200000
    const int* src = ei;
    const int* dst = ei + e;

    const int nb = (n + BINSZ - 1) >> BINBITS;   // 391

    size_t recB  = (((size_t)e + 4 * (size_t)nb) * 4 + 15) & ~(size_t)15;  // padded bins
    size_t bcB   = ((size_t)nb * EBC * 4 + 15) & ~(size_t)15;
    size_t bsB   = ((size_t)(2 * nb + 2) * 4 + 15) & ~(size_t)15;
    size_t ctB   = ((size_t)(3 * nb) * 4 + 15) & ~(size_t)15;
    size_t dinvB = ((size_t)n * 4 + 15) & ~(size_t)15;
    size_t degB  = ((size_t)n * 4 + 15) & ~(size_t)15;
    size_t gB    = ((size_t)n * 4 + 15) & ~(size_t)15;
    size_t y4qB  = ((size_t)n * 16 + 15) & ~(size_t)15;
    size_t fixed = recB + bcB + bsB + ctB + dinvB + degB + gB + y4qB;

    auto arena_sz = [&](int s) { return (size_t)nb * s * (2 * BINSZ) * 8; };

    int split;
    if      (ws_size >= fixed + arena_sz(8)) split = 8;
    else if (ws_size >= fixed + arena_sz(4)) split = 4;
    else if (ws_size >= fixed + arena_sz(2)) split = 2;
    else                                     split = 1;

    char* p = (char*)d_ws;
    uint32_t*   records  = (uint32_t*)p;      p += recB;
    uint32_t*   bc       = (uint32_t*)p;      p += bcB;
    uint32_t*   binStart = (uint32_t*)p;      p += bsB;
    uint32_t*   binSum   = binStart + nb + 1;
    uint32_t*   counters = (uint32_t*)p;      p += ctB;    // cntD | cntA | cntO
    float*      dinv     = (float*)p;         p += dinvB;
    uint32_t*   deg      = (uint32_t*)p;      p += degB;
    float*      gbuf     = (float*)p;         p += gB;
    ulonglong2* y4q      = (ulonglong2*)p;    p += y4qB;
    void*       arena    = (void*)p;          // partials (deg/agg/out reuse sequentially)

    const float4* x4 = (const float4*)x;
    uint32_t* cntD = counters;
    uint32_t* cntA = counters + nb;
    uint32_t* cntO = counters + 2 * nb;

    countK<<<EBC, THR, 0, stream>>>(dst, bc, counters, e, nb);
    scan1K<<<nb, EBC, 0, stream>>>(bc, binSum);
    scan2K<<<1, 512, 0, stream>>>(binSum, binStart, records, nb);
    fillK <<<EBC, THR, 0, stream>>>(src, dst, bc, binStart, records, e, nb);

    degY<<<nb * split, THR, 0, stream>>>(records, binStart, x4, (uint32_t*)arena,
                                         dinv, deg, y4q, cntD, split, n);
    aggT<<<nb * split, THR, 0, stream>>>(records, binStart, y4q,
                                         (unsigned long long*)arena, dinv, deg, x4,
                                         W1, b1, W2, gbuf, cntA, split, n);
    outF<<<nb * split, THR, 0, stream>>>(records, binStart, gbuf, (float*)arena,
                                         dinv, b2, out, cntO, split, n);
}

// Round 12
// 102.469 us; speedup vs baseline: 13.2934x; 13.2934x over previous
//
#include <hip/hip_runtime.h>
#include <math.h>
#include <stdint.h>

// 2-layer GCN anomaly scorer — binned counting-sort + LDS accumulation.
// R4: device atomics write through HBM -> 984us. R5: binned LDS 358us.
// R6: split4 -> 315us. R7: 2-level scan -> 160us. R8: split8 + u64 packed
// LDS atomics -> 115us. R9: EBC=256 + XCD swizzle + exact i64 -> 105us.
// R10: uint4-vectorized sweeps + padded bins -> 97us. R11 FAILED (1362us):
// last-block-merge w/ __threadfence = device-scope fence = cross-XCD L2
// writeback per block -> 20x slowdown. R12: revert to R10 separate-kernel
// structure (dispatch boundary = free ordering), keep scan2K|gapK fusion,
// raise split 8->16 (ws is ~268MB; more latency-hiding for gather sweeps).
//
// Math: agg[d] = dinv[d]*(sum_{s->d} y[s] + y[d]),  y = dinv.*x
//       g      = dinv .* (relu(agg@W1+b1)@W2)
//       out[d] = sigmoid(dinv[d]*(sum_{s->d} g[s] + g[d]) + b2)
// Fixed-point: q(v) = rn((v+16)*2^21); fields (f0,f1),(f2,f3) in two u64s.

#define BINBITS 8
#define BINSZ   256
#define NBMAX   512
#define EBC     256      // edge-chunk blocks for count/fill
#define THR     256
#define QS      2097152.0f   // 2^21
#define SENT    0xFFFFFFFFu

__device__ __forceinline__ uint32_t packq(float v) {
    return __float2uint_rn(fmaf(v, QS, 16.0f * QS));
}

// ---------------- sort phase ----------------

__global__ void countK(const int* __restrict__ dst, uint32_t* __restrict__ bc,
                       int e, int nb) {
    __shared__ uint32_t cnt[NBMAX];
    int t = threadIdx.x, b = blockIdx.x;
    for (int i = t; i < nb; i += THR) cnt[i] = 0;
    __syncthreads();
    int epb = (e + EBC - 1) / EBC;
    int lo = b * epb, hi = min(e, lo + epb);
    if (((lo | hi) & 3) == 0 && (((uintptr_t)dst & 15) == 0)) {
        const int4* dst4 = (const int4*)dst;
        for (int i = lo / 4 + t; i < hi / 4; i += THR) {
            int4 v = dst4[i];
            atomicAdd(&cnt[((unsigned)v.x) >> BINBITS], 1u);
            atomicAdd(&cnt[((unsigned)v.y) >> BINBITS], 1u);
            atomicAdd(&cnt[((unsigned)v.z) >> BINBITS], 1u);
            atomicAdd(&cnt[((unsigned)v.w) >> BINBITS], 1u);
        }
    } else {
        for (int i = lo + t; i < hi; i += THR)
            atomicAdd(&cnt[((unsigned)dst[i]) >> BINBITS], 1u);
    }
    __syncthreads();
    for (int i = t; i < nb; i += THR) bc[(size_t)i * EBC + b] = cnt[i];
}

// per-bin exclusive scan of the EBC per-block counts (block == EBC threads)
__global__ void scan1K(uint32_t* __restrict__ bc, uint32_t* __restrict__ binSum) {
    __shared__ uint32_t s[EBC];
    int t = threadIdx.x, bin = blockIdx.x;
    uint32_t v = bc[(size_t)bin * EBC + t];
    s[t] = v;
    __syncthreads();
    for (int off = 1; off < EBC; off <<= 1) {
        uint32_t u = (t >= off) ? s[t - off] : 0u;
        __syncthreads();
        s[t] += u;
        __syncthreads();
    }
    bc[(size_t)bin * EBC + t] = s[t] - v;           // exclusive
    if (t == EBC - 1) binSum[bin] = s[t];
}

// padded (multiple-of-4) exclusive scan of bin sums -> binStart; also writes
// the <=3 sentinel pad slots per bin directly (absorbs gapK).
__global__ void scan2K(const uint32_t* __restrict__ binSum,
                       uint32_t* __restrict__ binStart,
                       uint32_t* __restrict__ records, int nb) {
    __shared__ uint32_t s[512];
    int t = threadIdx.x;
    uint32_t real = (t < nb) ? binSum[t] : 0u;
    uint32_t v = (real + 3u) & ~3u;
    s[t] = v;
    __syncthreads();
    for (int off = 1; off < 512; off <<= 1) {
        uint32_t u = (t >= off) ? s[t - off] : 0u;
        __syncthreads();
        s[t] += u;
        __syncthreads();
    }
    if (t < nb) {
        uint32_t start = s[t] - v;
        binStart[t] = start;
        for (uint32_t q = start + real; q < start + v; ++q) records[q] = SENT;
    }
    if (t == nb - 1) binStart[nb] = s[t];           // padded total
}

__global__ void fillK(const int* __restrict__ src, const int* __restrict__ dst,
                      const uint32_t* __restrict__ bc,
                      const uint32_t* __restrict__ binStart,
                      uint32_t* __restrict__ records, int e, int nb) {
    __shared__ uint32_t cur[NBMAX];
    int t = threadIdx.x;
    // XCD-contiguous chunk swizzle (R9): same-XCD blocks take contiguous
    // edge chunks so shared record lines stay in one XCD's L2.
    int b = (blockIdx.x & 7) * (EBC / 8) + (blockIdx.x >> 3);
    for (int i = t; i < nb; i += THR)
        cur[i] = bc[(size_t)i * EBC + b] + binStart[i];
    __syncthreads();
    int epb = (e + EBC - 1) / EBC;
    int lo = b * epb, hi = min(e, lo + epb);
    if (((lo | hi) & 3) == 0 && (((uintptr_t)src & 15) == 0) && (((uintptr_t)dst & 15) == 0)) {
        const int4* src4 = (const int4*)src;
        const int4* dst4 = (const int4*)dst;
        for (int i = lo / 4 + t; i < hi / 4; i += THR) {
            int4 dv = dst4[i];
            int4 sv = src4[i];
            unsigned d0 = (unsigned)dv.x, d1 = (unsigned)dv.y;
            unsigned d2 = (unsigned)dv.z, d3 = (unsigned)dv.w;
            uint32_t p0 = atomicAdd(&cur[d0 >> BINBITS], 1u);
            records[p0] = (((unsigned)sv.x) << BINBITS) | (d0 & (BINSZ - 1));
            uint32_t p1 = atomicAdd(&cur[d1 >> BINBITS], 1u);
            records[p1] = (((unsigned)sv.y) << BINBITS) | (d1 & (BINSZ - 1));
            uint32_t p2 = atomicAdd(&cur[d2 >> BINBITS], 1u);
            records[p2] = (((unsigned)sv.z) << BINBITS) | (d2 & (BINSZ - 1));
            uint32_t p3 = atomicAdd(&cur[d3 >> BINBITS], 1u);
            records[p3] = (((unsigned)sv.w) << BINBITS) | (d3 & (BINSZ - 1));
        }
    } else {
        for (int i = lo + t; i < hi; i += THR) {
            unsigned d = (unsigned)dst[i];
            unsigned s = (unsigned)src[i];
            uint32_t slot = atomicAdd(&cur[d >> BINBITS], 1u);
            records[slot] = (s << BINBITS) | (d & (BINSZ - 1));
        }
    }
}

// ---------------- degree / dinv / packed y ----------------

__global__ void deg_part(const uint32_t* __restrict__ records,
                         const uint32_t* __restrict__ binStart,
                         uint32_t* __restrict__ histP, int split) {
    __shared__ uint32_t hist[BINSZ];
    int t = threadIdx.x;
    int bin = blockIdx.x / split, sub = blockIdx.x % split;
    hist[t] = 0u;
    __syncthreads();
    uint32_t lo = binStart[bin], hi = binStart[bin + 1];
    uint32_t chunk = (((hi - lo + split - 1) / split) + 3u) & ~3u;
    uint32_t slo = lo + sub * chunk;
    uint32_t shi = min(hi, slo + chunk);
    const uint4* rec4 = (const uint4*)records;
    for (uint32_t i = slo / 4 + t; i < shi / 4; i += THR) {
        uint4 r = rec4[i];
        if (r.x != SENT) atomicAdd(&hist[r.x & (BINSZ - 1)], 1u);
        if (r.y != SENT) atomicAdd(&hist[r.y & (BINSZ - 1)], 1u);
        if (r.z != SENT) atomicAdd(&hist[r.z & (BINSZ - 1)], 1u);
        if (r.w != SENT) atomicAdd(&hist[r.w & (BINSZ - 1)], 1u);
    }
    __syncthreads();
    histP[(size_t)blockIdx.x * BINSZ + t] = hist[t];
}

__global__ void mergeDinvY(const uint32_t* __restrict__ histP,
                           const float4* __restrict__ x4,
                           float* __restrict__ dinv, uint32_t* __restrict__ deg,
                           ulonglong2* __restrict__ y4q, int split, int n) {
    int t = threadIdx.x, bin = blockIdx.x;
    int node = (bin << BINBITS) + t;
    if (node >= n) return;
    uint32_t c = 0;
    for (int s = 0; s < split; ++s)
        c += histP[(size_t)(bin * split + s) * BINSZ + t];
    float dd = rsqrtf(1.0f + (float)c);
    dinv[node] = dd;
    deg[node] = c;
    float4 xv = x4[node];
    uint32_t q0 = packq(dd * xv.x), q1 = packq(dd * xv.y);
    uint32_t q2 = packq(dd * xv.z), q3 = packq(dd * xv.w);
    ulonglong2 p;
    p.x = ((unsigned long long)q1 << 32) | q0;
    p.y = ((unsigned long long)q3 << 32) | q2;
    y4q[node] = p;
}

// ---------------- layer-1 aggregation (packed u64 atomics) ----------------

__global__ void agg_part(const uint32_t* __restrict__ records,
                         const uint32_t* __restrict__ binStart,
                         const ulonglong2* __restrict__ y4q,
                         unsigned long long* __restrict__ aggP, int split) {
    __shared__ unsigned long long acc[2 * BINSZ];
    int t = threadIdx.x;
    int bin = blockIdx.x / split, sub = blockIdx.x % split;
    acc[t] = 0ull;
    acc[BINSZ + t] = 0ull;
    __syncthreads();
    uint32_t lo = binStart[bin], hi = binStart[bin + 1];
    uint32_t chunk = (((hi - lo + split - 1) / split) + 3u) & ~3u;
    uint32_t slo = lo + sub * chunk;
    uint32_t shi = min(hi, slo + chunk);
    const uint4* rec4 = (const uint4*)records;
    for (uint32_t i = slo / 4 + t; i < shi / 4; i += THR) {
        uint4 r = rec4[i];
        // issue all 4 gathers before the atomics (sentinel -> safe idx 0)
        unsigned s0 = (r.x == SENT) ? 0u : (r.x >> BINBITS);
        unsigned s1 = (r.y == SENT) ? 0u : (r.y >> BINBITS);
        unsigned s2 = (r.z == SENT) ? 0u : (r.z >> BINBITS);
        unsigned s3 = (r.w == SENT) ? 0u : (r.w >> BINBITS);
        ulonglong2 y0 = y4q[s0];
        ulonglong2 y1 = y4q[s1];
        ulonglong2 y2 = y4q[s2];
        ulonglong2 y3 = y4q[s3];
        if (r.x != SENT) { unsigned d = r.x & (BINSZ - 1); atomicAdd(&acc[d], y0.x); atomicAdd(&acc[BINSZ + d], y0.y); }
        if (r.y != SENT) { unsigned d = r.y & (BINSZ - 1); atomicAdd(&acc[d], y1.x); atomicAdd(&acc[BINSZ + d], y1.y); }
        if (r.z != SENT) { unsigned d = r.z & (BINSZ - 1); atomicAdd(&acc[d], y2.x); atomicAdd(&acc[BINSZ + d], y2.y); }
        if (r.w != SENT) { unsigned d = r.w & (BINSZ - 1); atomicAdd(&acc[d], y3.x); atomicAdd(&acc[BINSZ + d], y3.y); }
    }
    __syncthreads();
    unsigned long long* p = aggP + (size_t)blockIdx.x * (2 * BINSZ);
    p[t] = acc[t];
    p[BINSZ + t] = acc[BINSZ + t];
}

__global__ void mergeAggT(const unsigned long long* __restrict__ aggP,
                          const float* __restrict__ dinv, const uint32_t* __restrict__ deg,
                          const float4* __restrict__ x4,
                          const float* __restrict__ W1, const float* __restrict__ b1,
                          const float* __restrict__ W2,
                          float* __restrict__ g, int split, int n) {
    __shared__ float sW1[128], sb1[32], sW2[32];
    int t = threadIdx.x, bin = blockIdx.x;
    if (t < 128) sW1[t] = W1[t];
    else if (t < 160) sb1[t - 128] = b1[t - 128];
    else if (t < 192) sW2[t - 160] = W2[t - 160];
    __syncthreads();
    int node = (bin << BINBITS) + t;
    if (node >= n) return;
    unsigned long long s0lo = 0, s0hi = 0, s1lo = 0, s1hi = 0;
    size_t base = (size_t)bin * split * (2 * BINSZ);
    for (int s2 = 0; s2 < split; ++s2) {
        const unsigned long long* q = aggP + base + (size_t)s2 * (2 * BINSZ);
        unsigned long long P0 = q[t], P1 = q[BINSZ + t];
        s0lo += (uint32_t)P0; s0hi += (uint32_t)(P0 >> 32);
        s1lo += (uint32_t)P1; s1hi += (uint32_t)(P1 >> 32);
    }
    // exact de-bias + conversion (R9): split at 2^21 so both halves are exact.
    long long bias = (long long)deg[node] << 25;   // deg * 16 * 2^21
    const float inv = 1.0f / QS;
    long long v0 = (long long)s0lo - bias, v1 = (long long)s0hi - bias;
    long long v2 = (long long)s1lo - bias, v3 = (long long)s1hi - bias;
    float T0 = (float)(v0 >> 21) + (float)(v0 & 0x1FFFFF) * inv;
    float T1 = (float)(v1 >> 21) + (float)(v1 & 0x1FFFFF) * inv;
    float T2 = (float)(v2 >> 21) + (float)(v2 & 0x1FFFFF) * inv;
    float T3 = (float)(v3 >> 21) + (float)(v3 & 0x1FFFFF) * inv;
    float dd = dinv[node];
    float4 xv = x4[node];
    float a0 = dd * (T0 + dd * xv.x), a1 = dd * (T1 + dd * xv.y);
    float a2 = dd * (T2 + dd * xv.z), a3 = dd * (T3 + dd * xv.w);
    float hv = 0.f;
#pragma unroll
    for (int j = 0; j < 32; ++j) {
        float o = fmaf(a0, sW1[j], fmaf(a1, sW1[32 + j],
                  fmaf(a2, sW1[64 + j], fmaf(a3, sW1[96 + j], sb1[j]))));
        hv += fmaxf(o, 0.f) * sW2[j];
    }
    g[node] = dd * hv;
}

// ---------------- layer-2 ----------------

__global__ void out_part(const uint32_t* __restrict__ records,
                         const uint32_t* __restrict__ binStart,
                         const float* __restrict__ g,
                         float* __restrict__ outP, int split) {
    __shared__ float accg[BINSZ];
    int t = threadIdx.x;
    int bin = blockIdx.x / split, sub = blockIdx.x % split;
    accg[t] = 0.f;
    __syncthreads();
    uint32_t lo = binStart[bin], hi = binStart[bin + 1];
    uint32_t chunk = (((hi - lo + split - 1) / split) + 3u) & ~3u;
    uint32_t slo = lo + sub * chunk;
    uint32_t shi = min(hi, slo + chunk);
    const uint4* rec4 = (const uint4*)records;
    for (uint32_t i = slo / 4 + t; i < shi / 4; i += THR) {
        uint4 r = rec4[i];
        unsigned s0 = (r.x == SENT) ? 0u : (r.x >> BINBITS);
        unsigned s1 = (r.y == SENT) ? 0u : (r.y >> BINBITS);
        unsigned s2 = (r.z == SENT) ? 0u : (r.z >> BINBITS);
        unsigned s3 = (r.w == SENT) ? 0u : (r.w >> BINBITS);
        float g0 = g[s0], g1 = g[s1], g2 = g[s2], g3 = g[s3];
        if (r.x != SENT) atomicAdd(&accg[r.x & (BINSZ - 1)], g0);
        if (r.y != SENT) atomicAdd(&accg[r.y & (BINSZ - 1)], g1);
        if (r.z != SENT) atomicAdd(&accg[r.z & (BINSZ - 1)], g2);
        if (r.w != SENT) atomicAdd(&accg[r.w & (BINSZ - 1)], g3);
    }
    __syncthreads();
    outP[(size_t)blockIdx.x * BINSZ + t] = accg[t];
}

__global__ void mergeOutK(const float* __restrict__ outP, const float* __restrict__ g,
                          const float* __restrict__ dinv, const float* __restrict__ b2,
                          float* __restrict__ out, int split, int n) {
    int t = threadIdx.x, bin = blockIdx.x;
    int node = (bin << BINBITS) + t;
    if (node >= n) return;
    float s = 0.f;
    size_t base = (size_t)bin * split * BINSZ;
    for (int k = 0; k < split; ++k)
        s += outP[base + (size_t)k * BINSZ + t];
    float v = dinv[node] * (s + g[node]) + b2[0];
    out[node] = 1.0f / (1.0f + expf(-v));
}

// ---------------- launcher ----------------

extern "C" void kernel_launch(void* const* d_in, const int* in_sizes, int n_in,
                              void* d_out, int out_size, void* d_ws, size_t ws_size,
                              hipStream_t stream) {
    const float* x  = (const float*)d_in[0];
    const int*   ei = (const int*)d_in[1];
    const float* W1 = (const float*)d_in[2];
    const float* b1 = (const float*)d_in[3];
    const float* W2 = (const float*)d_in[4];
    const float* b2 = (const float*)d_in[5];
    float* out = (float*)d_out;

    const int n = in_sizes[0] / 4;            // 100000
    const int e = in_sizes[1] / 2;            // 3200000
    const int* src = ei;
    const int* dst = ei + e;

    const int nb = (n + BINSZ - 1) >> BINBITS;   // 391

    size_t recB  = (((size_t)e + 4 * (size_t)nb) * 4 + 15) & ~(size_t)15;  // padded bins
    size_t bcB   = ((size_t)nb * EBC * 4 + 15) & ~(size_t)15;
    size_t bsB   = ((size_t)(2 * nb + 2) * 4 + 15) & ~(size_t)15;
    size_t dinvB = ((size_t)n * 4 + 15) & ~(size_t)15;
    size_t degB  = ((size_t)n * 4 + 15) & ~(size_t)15;
    size_t gB    = ((size_t)n * 4 + 15) & ~(size_t)15;
    size_t y4qB  = ((size_t)n * 16 + 15) & ~(size_t)15;
    size_t fixed = recB + bcB + bsB + dinvB + degB + gB + y4qB;

    auto arena_sz = [&](int s) { return (size_t)nb * s * (2 * BINSZ) * 8; };

    int split;
    if      (ws_size >= fixed + arena_sz(16)) split = 16;
    else if (ws_size >= fixed + arena_sz(8))  split = 8;
    else if (ws_size >= fixed + arena_sz(4))  split = 4;
    else if (ws_size >= fixed + arena_sz(2))  split = 2;
    else                                      split = 1;

    char* p = (char*)d_ws;
    uint32_t*   records  = (uint32_t*)p;      p += recB;
    uint32_t*   bc       = (uint32_t*)p;      p += bcB;
    uint32_t*   binStart = (uint32_t*)p;      p += bsB;
    uint32_t*   binSum   = binStart + nb + 1;
    float*      dinv     = (float*)p;         p += dinvB;
    uint32_t*   deg      = (uint32_t*)p;      p += degB;
    float*      gbuf     = (float*)p;         p += gB;
    ulonglong2* y4q      = (ulonglong2*)p;    p += y4qB;
    void*       arena    = (void*)p;          // partials (deg/agg/out reuse sequentially)

    const float4* x4 = (const float4*)x;

    countK<<<EBC, THR, 0, stream>>>(dst, bc, e, nb);
    scan1K<<<nb, EBC, 0, stream>>>(bc, binSum);
    scan2K<<<1, 512, 0, stream>>>(binSum, binStart, records, nb);
    fillK <<<EBC, THR, 0, stream>>>(src, dst, bc, binStart, records, e, nb);

    deg_part<<<nb * split, THR, 0, stream>>>(records, binStart, (uint32_t*)arena, split);
    mergeDinvY<<<nb, THR, 0, stream>>>((const uint32_t*)arena, x4, dinv, deg, y4q, split, n);
    agg_part<<<nb * split, THR, 0, stream>>>(records, binStart, y4q,
                                             (unsigned long long*)arena, split);
    mergeAggT<<<nb, THR, 0, stream>>>((const unsigned long long*)arena, dinv, deg, x4,
                                      W1, b1, W2, gbuf, split, n);
    out_part<<<nb * split, THR, 0, stream>>>(records, binStart, gbuf, (float*)arena, split);
    mergeOutK<<<nb, THR, 0, stream>>>((const float*)arena, gbuf, dinv, b2, out, split, n);
}

// Round 13
// 90.322 us; speedup vs baseline: 15.0813x; 1.1345x over previous
//
#include <hip/hip_runtime.h>
#include <math.h>
#include <stdint.h>

// 2-layer GCN anomaly scorer — binned counting-sort + LDS accumulation.
// R4: device atomics write through HBM -> 984us. R5: binned LDS 358us.
// R6: split4 -> 315us. R7: 2-level scan -> 160us. R8: split8 + u64 packed
// LDS atomics -> 115us. R9: EBC=256 + XCD swizzle + exact i64 -> 105us.
// R10: uint4 sweeps + padded bins -> 97us. R11 FAILED (1362us): per-block
// __threadfence = cross-XCD L2 writeback -> 14x. R12: split16 regressed
// (102us, 2x partial traffic). R13: split capped at 8; deg and out phases
// fused to single 1024-thread-per-bin kernels (whole bin per block -> no
// partials, no fence, 2 fewer dispatches).
//
// Math: agg[d] = dinv[d]*(sum_{s->d} y[s] + y[d]),  y = dinv.*x
//       g      = dinv .* (relu(agg@W1+b1)@W2)
//       out[d] = sigmoid(dinv[d]*(sum_{s->d} g[s] + g[d]) + b2)
// Fixed-point: q(v) = rn((v+16)*2^21); fields (f0,f1),(f2,f3) in two u64s.

#define BINBITS 8
#define BINSZ   256
#define NBMAX   512
#define EBC     256      // edge-chunk blocks for count/fill
#define THR     256
#define QS      2097152.0f   // 2^21
#define SENT    0xFFFFFFFFu

__device__ __forceinline__ uint32_t packq(float v) {
    return __float2uint_rn(fmaf(v, QS, 16.0f * QS));
}

// ---------------- sort phase ----------------

__global__ void countK(const int* __restrict__ dst, uint32_t* __restrict__ bc,
                       int e, int nb) {
    __shared__ uint32_t cnt[NBMAX];
    int t = threadIdx.x, b = blockIdx.x;
    for (int i = t; i < nb; i += THR) cnt[i] = 0;
    __syncthreads();
    int epb = (e + EBC - 1) / EBC;
    int lo = b * epb, hi = min(e, lo + epb);
    if (((lo | hi) & 3) == 0 && (((uintptr_t)dst & 15) == 0)) {
        const int4* dst4 = (const int4*)dst;
        for (int i = lo / 4 + t; i < hi / 4; i += THR) {
            int4 v = dst4[i];
            atomicAdd(&cnt[((unsigned)v.x) >> BINBITS], 1u);
            atomicAdd(&cnt[((unsigned)v.y) >> BINBITS], 1u);
            atomicAdd(&cnt[((unsigned)v.z) >> BINBITS], 1u);
            atomicAdd(&cnt[((unsigned)v.w) >> BINBITS], 1u);
        }
    } else {
        for (int i = lo + t; i < hi; i += THR)
            atomicAdd(&cnt[((unsigned)dst[i]) >> BINBITS], 1u);
    }
    __syncthreads();
    for (int i = t; i < nb; i += THR) bc[(size_t)i * EBC + b] = cnt[i];
}

// per-bin exclusive scan of the EBC per-block counts (block == EBC threads)
__global__ void scan1K(uint32_t* __restrict__ bc, uint32_t* __restrict__ binSum) {
    __shared__ uint32_t s[EBC];
    int t = threadIdx.x, bin = blockIdx.x;
    uint32_t v = bc[(size_t)bin * EBC + t];
    s[t] = v;
    __syncthreads();
    for (int off = 1; off < EBC; off <<= 1) {
        uint32_t u = (t >= off) ? s[t - off] : 0u;
        __syncthreads();
        s[t] += u;
        __syncthreads();
    }
    bc[(size_t)bin * EBC + t] = s[t] - v;           // exclusive
    if (t == EBC - 1) binSum[bin] = s[t];
}

// padded (multiple-of-4) exclusive scan of bin sums -> binStart; also writes
// the <=3 sentinel pad slots per bin directly.
__global__ void scan2K(const uint32_t* __restrict__ binSum,
                       uint32_t* __restrict__ binStart,
                       uint32_t* __restrict__ records, int nb) {
    __shared__ uint32_t s[512];
    int t = threadIdx.x;
    uint32_t real = (t < nb) ? binSum[t] : 0u;
    uint32_t v = (real + 3u) & ~3u;
    s[t] = v;
    __syncthreads();
    for (int off = 1; off < 512; off <<= 1) {
        uint32_t u = (t >= off) ? s[t - off] : 0u;
        __syncthreads();
        s[t] += u;
        __syncthreads();
    }
    if (t < nb) {
        uint32_t start = s[t] - v;
        binStart[t] = start;
        for (uint32_t q = start + real; q < start + v; ++q) records[q] = SENT;
    }
    if (t == nb - 1) binStart[nb] = s[t];           // padded total
}

__global__ void fillK(const int* __restrict__ src, const int* __restrict__ dst,
                      const uint32_t* __restrict__ bc,
                      const uint32_t* __restrict__ binStart,
                      uint32_t* __restrict__ records, int e, int nb) {
    __shared__ uint32_t cur[NBMAX];
    int t = threadIdx.x;
    // XCD-contiguous chunk swizzle (R9): same-XCD blocks take contiguous
    // edge chunks so shared record lines stay in one XCD's L2.
    int b = (blockIdx.x & 7) * (EBC / 8) + (blockIdx.x >> 3);
    for (int i = t; i < nb; i += THR)
        cur[i] = bc[(size_t)i * EBC + b] + binStart[i];
    __syncthreads();
    int epb = (e + EBC - 1) / EBC;
    int lo = b * epb, hi = min(e, lo + epb);
    if (((lo | hi) & 3) == 0 && (((uintptr_t)src & 15) == 0) && (((uintptr_t)dst & 15) == 0)) {
        const int4* src4 = (const int4*)src;
        const int4* dst4 = (const int4*)dst;
        for (int i = lo / 4 + t; i < hi / 4; i += THR) {
            int4 dv = dst4[i];
            int4 sv = src4[i];
            unsigned d0 = (unsigned)dv.x, d1 = (unsigned)dv.y;
            unsigned d2 = (unsigned)dv.z, d3 = (unsigned)dv.w;
            uint32_t p0 = atomicAdd(&cur[d0 >> BINBITS], 1u);
            records[p0] = (((unsigned)sv.x) << BINBITS) | (d0 & (BINSZ - 1));
            uint32_t p1 = atomicAdd(&cur[d1 >> BINBITS], 1u);
            records[p1] = (((unsigned)sv.y) << BINBITS) | (d1 & (BINSZ - 1));
            uint32_t p2 = atomicAdd(&cur[d2 >> BINBITS], 1u);
            records[p2] = (((unsigned)sv.z) << BINBITS) | (d2 & (BINSZ - 1));
            uint32_t p3 = atomicAdd(&cur[d3 >> BINBITS], 1u);
            records[p3] = (((unsigned)sv.w) << BINBITS) | (d3 & (BINSZ - 1));
        }
    } else {
        for (int i = lo + t; i < hi; i += THR) {
            unsigned d = (unsigned)dst[i];
            unsigned s = (unsigned)src[i];
            uint32_t slot = atomicAdd(&cur[d >> BINBITS], 1u);
            records[slot] = (s << BINBITS) | (d & (BINSZ - 1));
        }
    }
}

// ---------------- degree / dinv / packed y (whole bin per 1024-thr block) ----

__global__ __launch_bounds__(1024)
void degInline(const uint32_t* __restrict__ records,
               const uint32_t* __restrict__ binStart,
               const float4* __restrict__ x4,
               float* __restrict__ dinv, uint32_t* __restrict__ deg,
               ulonglong2* __restrict__ y4q, int n) {
    __shared__ uint32_t hist[BINSZ];
    int t = threadIdx.x, bin = blockIdx.x;
    if (t < BINSZ) hist[t] = 0u;
    __syncthreads();
    uint32_t lo = binStart[bin], hi = binStart[bin + 1];
    const uint4* rec4 = (const uint4*)records;
    for (uint32_t i = lo / 4 + t; i < hi / 4; i += 1024) {
        uint4 r = rec4[i];
        if (r.x != SENT) atomicAdd(&hist[r.x & (BINSZ - 1)], 1u);
        if (r.y != SENT) atomicAdd(&hist[r.y & (BINSZ - 1)], 1u);
        if (r.z != SENT) atomicAdd(&hist[r.z & (BINSZ - 1)], 1u);
        if (r.w != SENT) atomicAdd(&hist[r.w & (BINSZ - 1)], 1u);
    }
    __syncthreads();
    if (t >= BINSZ) return;
    int node = (bin << BINBITS) + t;
    if (node >= n) return;
    uint32_t c = hist[t];
    float dd = rsqrtf(1.0f + (float)c);
    dinv[node] = dd;
    deg[node] = c;
    float4 xv = x4[node];
    uint32_t q0 = packq(dd * xv.x), q1 = packq(dd * xv.y);
    uint32_t q2 = packq(dd * xv.z), q3 = packq(dd * xv.w);
    ulonglong2 p;
    p.x = ((unsigned long long)q1 << 32) | q0;
    p.y = ((unsigned long long)q3 << 32) | q2;
    y4q[node] = p;
}

// ---------------- layer-1 aggregation (packed u64 atomics, split8) ----------

__global__ void agg_part(const uint32_t* __restrict__ records,
                         const uint32_t* __restrict__ binStart,
                         const ulonglong2* __restrict__ y4q,
                         unsigned long long* __restrict__ aggP, int split) {
    __shared__ unsigned long long acc[2 * BINSZ];
    int t = threadIdx.x;
    int bin = blockIdx.x / split, sub = blockIdx.x % split;
    acc[t] = 0ull;
    acc[BINSZ + t] = 0ull;
    __syncthreads();
    uint32_t lo = binStart[bin], hi = binStart[bin + 1];
    uint32_t chunk = (((hi - lo + split - 1) / split) + 3u) & ~3u;
    uint32_t slo = lo + sub * chunk;
    uint32_t shi = min(hi, slo + chunk);
    const uint4* rec4 = (const uint4*)records;
    for (uint32_t i = slo / 4 + t; i < shi / 4; i += THR) {
        uint4 r = rec4[i];
        // issue all 4 gathers before the atomics (sentinel -> safe idx 0)
        unsigned s0 = (r.x == SENT) ? 0u : (r.x >> BINBITS);
        unsigned s1 = (r.y == SENT) ? 0u : (r.y >> BINBITS);
        unsigned s2 = (r.z == SENT) ? 0u : (r.z >> BINBITS);
        unsigned s3 = (r.w == SENT) ? 0u : (r.w >> BINBITS);
        ulonglong2 y0 = y4q[s0];
        ulonglong2 y1 = y4q[s1];
        ulonglong2 y2 = y4q[s2];
        ulonglong2 y3 = y4q[s3];
        if (r.x != SENT) { unsigned d = r.x & (BINSZ - 1); atomicAdd(&acc[d], y0.x); atomicAdd(&acc[BINSZ + d], y0.y); }
        if (r.y != SENT) { unsigned d = r.y & (BINSZ - 1); atomicAdd(&acc[d], y1.x); atomicAdd(&acc[BINSZ + d], y1.y); }
        if (r.z != SENT) { unsigned d = r.z & (BINSZ - 1); atomicAdd(&acc[d], y2.x); atomicAdd(&acc[BINSZ + d], y2.y); }
        if (r.w != SENT) { unsigned d = r.w & (BINSZ - 1); atomicAdd(&acc[d], y3.x); atomicAdd(&acc[BINSZ + d], y3.y); }
    }
    __syncthreads();
    unsigned long long* p = aggP + (size_t)blockIdx.x * (2 * BINSZ);
    p[t] = acc[t];
    p[BINSZ + t] = acc[BINSZ + t];
}

__global__ void mergeAggT(const unsigned long long* __restrict__ aggP,
                          const float* __restrict__ dinv, const uint32_t* __restrict__ deg,
                          const float4* __restrict__ x4,
                          const float* __restrict__ W1, const float* __restrict__ b1,
                          const float* __restrict__ W2,
                          float* __restrict__ g, int split, int n) {
    __shared__ float sW1[128], sb1[32], sW2[32];
    int t = threadIdx.x, bin = blockIdx.x;
    if (t < 128) sW1[t] = W1[t];
    else if (t < 160) sb1[t - 128] = b1[t - 128];
    else if (t < 192) sW2[t - 160] = W2[t - 160];
    __syncthreads();
    int node = (bin << BINBITS) + t;
    if (node >= n) return;
    unsigned long long s0lo = 0, s0hi = 0, s1lo = 0, s1hi = 0;
    size_t base = (size_t)bin * split * (2 * BINSZ);
    for (int s2 = 0; s2 < split; ++s2) {
        const unsigned long long* q = aggP + base + (size_t)s2 * (2 * BINSZ);
        unsigned long long P0 = q[t], P1 = q[BINSZ + t];
        s0lo += (uint32_t)P0; s0hi += (uint32_t)(P0 >> 32);
        s1lo += (uint32_t)P1; s1hi += (uint32_t)(P1 >> 32);
    }
    // exact de-bias + conversion (R9): split at 2^21 so both halves are exact.
    long long bias = (long long)deg[node] << 25;   // deg * 16 * 2^21
    const float inv = 1.0f / QS;
    long long v0 = (long long)s0lo - bias, v1 = (long long)s0hi - bias;
    long long v2 = (long long)s1lo - bias, v3 = (long long)s1hi - bias;
    float T0 = (float)(v0 >> 21) + (float)(v0 & 0x1FFFFF) * inv;
    float T1 = (float)(v1 >> 21) + (float)(v1 & 0x1FFFFF) * inv;
    float T2 = (float)(v2 >> 21) + (float)(v2 & 0x1FFFFF) * inv;
    float T3 = (float)(v3 >> 21) + (float)(v3 & 0x1FFFFF) * inv;
    float dd = dinv[node];
    float4 xv = x4[node];
    float a0 = dd * (T0 + dd * xv.x), a1 = dd * (T1 + dd * xv.y);
    float a2 = dd * (T2 + dd * xv.z), a3 = dd * (T3 + dd * xv.w);
    float hv = 0.f;
#pragma unroll
    for (int j = 0; j < 32; ++j) {
        float o = fmaf(a0, sW1[j], fmaf(a1, sW1[32 + j],
                  fmaf(a2, sW1[64 + j], fmaf(a3, sW1[96 + j], sb1[j]))));
        hv += fmaxf(o, 0.f) * sW2[j];
    }
    g[node] = dd * hv;
}

// ---------------- layer-2 + sigmoid (whole bin per 1024-thr block) ---------

__global__ __launch_bounds__(1024)
void outInline(const uint32_t* __restrict__ records,
               const uint32_t* __restrict__ binStart,
               const float* __restrict__ g, const float* __restrict__ dinv,
               const float* __restrict__ b2, float* __restrict__ out, int n) {
    __shared__ float accg[BINSZ];
    int t = threadIdx.x, bin = blockIdx.x;
    if (t < BINSZ) accg[t] = 0.f;
    __syncthreads();
    uint32_t lo = binStart[bin], hi = binStart[bin + 1];
    const uint4* rec4 = (const uint4*)records;
    for (uint32_t i = lo / 4 + t; i < hi / 4; i += 1024) {
        uint4 r = rec4[i];
        unsigned s0 = (r.x == SENT) ? 0u : (r.x >> BINBITS);
        unsigned s1 = (r.y == SENT) ? 0u : (r.y >> BINBITS);
        unsigned s2 = (r.z == SENT) ? 0u : (r.z >> BINBITS);
        unsigned s3 = (r.w == SENT) ? 0u : (r.w >> BINBITS);
        float g0 = g[s0], g1 = g[s1], g2 = g[s2], g3 = g[s3];
        if (r.x != SENT) atomicAdd(&accg[r.x & (BINSZ - 1)], g0);
        if (r.y != SENT) atomicAdd(&accg[r.y & (BINSZ - 1)], g1);
        if (r.z != SENT) atomicAdd(&accg[r.z & (BINSZ - 1)], g2);
        if (r.w != SENT) atomicAdd(&accg[r.w & (BINSZ - 1)], g3);
    }
    __syncthreads();
    if (t >= BINSZ) return;
    int node = (bin << BINBITS) + t;
    if (node >= n) return;
    float v = dinv[node] * (accg[t] + g[node]) + b2[0];
    out[node] = 1.0f / (1.0f + expf(-v));
}

// ---------------- launcher ----------------

extern "C" void kernel_launch(void* const* d_in, const int* in_sizes, int n_in,
                              void* d_out, int out_size, void* d_ws, size_t ws_size,
                              hipStream_t stream) {
    const float* x  = (const float*)d_in[0];
    const int*   ei = (const int*)d_in[1];
    const float* W1 = (const float*)d_in[2];
    const float* b1 = (const float*)d_in[3];
    const float* W2 = (const float*)d_in[4];
    const float* b2 = (const float*)d_in[5];
    float* out = (float*)d_out;

    const int n = in_sizes[0] / 4;            // 100000
    const int e = in_sizes[1] / 2;            // 3200000
    const int* src = ei;
    const int* dst = ei + e;

    const int nb = (n + BINSZ - 1) >> BINBITS;   // 391

    size_t recB  = (((size_t)e + 4 * (size_t)nb) * 4 + 15) & ~(size_t)15;  // padded bins
    size_t bcB   = ((size_t)nb * EBC * 4 + 15) & ~(size_t)15;
    size_t bsB   = ((size_t)(2 * nb + 2) * 4 + 15) & ~(size_t)15;
    size_t dinvB = ((size_t)n * 4 + 15) & ~(size_t)15;
    size_t degB  = ((size_t)n * 4 + 15) & ~(size_t)15;
    size_t gB    = ((size_t)n * 4 + 15) & ~(size_t)15;
    size_t y4qB  = ((size_t)n * 16 + 15) & ~(size_t)15;
    size_t fixed = recB + bcB + bsB + dinvB + degB + gB + y4qB;

    auto arena_sz = [&](int s) { return (size_t)nb * s * (2 * BINSZ) * 8; };

    int split;
    if      (ws_size >= fixed + arena_sz(8)) split = 8;
    else if (ws_size >= fixed + arena_sz(4)) split = 4;
    else if (ws_size >= fixed + arena_sz(2)) split = 2;
    else                                     split = 1;

    char* p = (char*)d_ws;
    uint32_t*   records  = (uint32_t*)p;      p += recB;
    uint32_t*   bc       = (uint32_t*)p;      p += bcB;
    uint32_t*   binStart = (uint32_t*)p;      p += bsB;
    uint32_t*   binSum   = binStart + nb + 1;
    float*      dinv     = (float*)p;         p += dinvB;
    uint32_t*   deg      = (uint32_t*)p;      p += degB;
    float*      gbuf     = (float*)p;         p += gB;
    ulonglong2* y4q      = (ulonglong2*)p;    p += y4qB;
    void*       arena    = (void*)p;          // agg partials

    const float4* x4 = (const float4*)x;

    countK<<<EBC, THR, 0, stream>>>(dst, bc, e, nb);
    scan1K<<<nb, EBC, 0, stream>>>(bc, binSum);
    scan2K<<<1, 512, 0, stream>>>(binSum, binStart, records, nb);
    fillK <<<EBC, THR, 0, stream>>>(src, dst, bc, binStart, records, e, nb);

    degInline<<<nb, 1024, 0, stream>>>(records, binStart, x4, dinv, deg, y4q, n);
    agg_part<<<nb * split, THR, 0, stream>>>(records, binStart, y4q,
                                             (unsigned long long*)arena, split);
    mergeAggT<<<nb, THR, 0, stream>>>((const unsigned long long*)arena, dinv, deg, x4,
                                      W1, b1, W2, gbuf, split, n);
    outInline<<<nb, 1024, 0, stream>>>(records, binStart, gbuf, dinv, b2, out, n);
}

// Round 14
// 83.794 us; speedup vs baseline: 16.2561x; 1.0779x over previous
//
#include <hip/hip_runtime.h>
#include <math.h>
#include <stdint.h>

// 2-layer GCN anomaly scorer — binned counting-sort + LDS accumulation.
// R4: device atomics write through HBM -> 984us. R5: binned LDS 358us.
// R6: split4 -> 315us. R7: 2-level scan -> 160us. R8: split8 + u64 packed
// LDS atomics -> 115us. R9: EBC=256 + XCD swizzle + exact i64 -> 105us.
// R10: uint4 sweeps + padded bins -> 97us. R11 FAILED (1362us): per-block
// __threadfence = cross-XCD L2 writeback. R12: split16 regressed (102us).
// R13: deg/out fused to whole-bin 1024-thr blocks -> 90us. R14: agg gets
// the same treatment (aggInline: whole bin, u64 LDS acc, fused transform,
// paired-iter ILP) — kills 25.6MB partial round-trip + merge dispatch.
//
// Math: agg[d] = dinv[d]*(sum_{s->d} y[s] + y[d]),  y = dinv.*x
//       g      = dinv .* (relu(agg@W1+b1)@W2)
//       out[d] = sigmoid(dinv[d]*(sum_{s->d} g[s] + g[d]) + b2)
// Fixed-point: q(v) = rn((v+16)*2^21); fields (f0,f1),(f2,f3) in two u64s.
// Max biased field sum: 21*2^21*deg(<=~80) ~ 3.5e9 < 2^32 -> no overflow.

#define BINBITS 8
#define BINSZ   256
#define NBMAX   512
#define EBC     256      // edge-chunk blocks for count/fill
#define THR     256
#define QS      2097152.0f   // 2^21
#define SENT    0xFFFFFFFFu

__device__ __forceinline__ uint32_t packq(float v) {
    return __float2uint_rn(fmaf(v, QS, 16.0f * QS));
}

// ---------------- sort phase ----------------

__global__ void countK(const int* __restrict__ dst, uint32_t* __restrict__ bc,
                       int e, int nb) {
    __shared__ uint32_t cnt[NBMAX];
    int t = threadIdx.x, b = blockIdx.x;
    for (int i = t; i < nb; i += THR) cnt[i] = 0;
    __syncthreads();
    int epb = (e + EBC - 1) / EBC;
    int lo = b * epb, hi = min(e, lo + epb);
    if (((lo | hi) & 3) == 0 && (((uintptr_t)dst & 15) == 0)) {
        const int4* dst4 = (const int4*)dst;
        for (int i = lo / 4 + t; i < hi / 4; i += THR) {
            int4 v = dst4[i];
            atomicAdd(&cnt[((unsigned)v.x) >> BINBITS], 1u);
            atomicAdd(&cnt[((unsigned)v.y) >> BINBITS], 1u);
            atomicAdd(&cnt[((unsigned)v.z) >> BINBITS], 1u);
            atomicAdd(&cnt[((unsigned)v.w) >> BINBITS], 1u);
        }
    } else {
        for (int i = lo + t; i < hi; i += THR)
            atomicAdd(&cnt[((unsigned)dst[i]) >> BINBITS], 1u);
    }
    __syncthreads();
    for (int i = t; i < nb; i += THR) bc[(size_t)i * EBC + b] = cnt[i];
}

// per-bin exclusive scan of the EBC per-block counts (block == EBC threads)
__global__ void scan1K(uint32_t* __restrict__ bc, uint32_t* __restrict__ binSum) {
    __shared__ uint32_t s[EBC];
    int t = threadIdx.x, bin = blockIdx.x;
    uint32_t v = bc[(size_t)bin * EBC + t];
    s[t] = v;
    __syncthreads();
    for (int off = 1; off < EBC; off <<= 1) {
        uint32_t u = (t >= off) ? s[t - off] : 0u;
        __syncthreads();
        s[t] += u;
        __syncthreads();
    }
    bc[(size_t)bin * EBC + t] = s[t] - v;           // exclusive
    if (t == EBC - 1) binSum[bin] = s[t];
}

// padded (multiple-of-4) exclusive scan of bin sums -> binStart; also writes
// the <=3 sentinel pad slots per bin directly.
__global__ void scan2K(const uint32_t* __restrict__ binSum,
                       uint32_t* __restrict__ binStart,
                       uint32_t* __restrict__ records, int nb) {
    __shared__ uint32_t s[512];
    int t = threadIdx.x;
    uint32_t real = (t < nb) ? binSum[t] : 0u;
    uint32_t v = (real + 3u) & ~3u;
    s[t] = v;
    __syncthreads();
    for (int off = 1; off < 512; off <<= 1) {
        uint32_t u = (t >= off) ? s[t - off] : 0u;
        __syncthreads();
        s[t] += u;
        __syncthreads();
    }
    if (t < nb) {
        uint32_t start = s[t] - v;
        binStart[t] = start;
        for (uint32_t q = start + real; q < start + v; ++q) records[q] = SENT;
    }
    if (t == nb - 1) binStart[nb] = s[t];           // padded total
}

__global__ void fillK(const int* __restrict__ src, const int* __restrict__ dst,
                      const uint32_t* __restrict__ bc,
                      const uint32_t* __restrict__ binStart,
                      uint32_t* __restrict__ records, int e, int nb) {
    __shared__ uint32_t cur[NBMAX];
    int t = threadIdx.x;
    // XCD-contiguous chunk swizzle (R9): same-XCD blocks take contiguous
    // edge chunks so shared record lines stay in one XCD's L2.
    int b = (blockIdx.x & 7) * (EBC / 8) + (blockIdx.x >> 3);
    for (int i = t; i < nb; i += THR)
        cur[i] = bc[(size_t)i * EBC + b] + binStart[i];
    __syncthreads();
    int epb = (e + EBC - 1) / EBC;
    int lo = b * epb, hi = min(e, lo + epb);
    if (((lo | hi) & 3) == 0 && (((uintptr_t)src & 15) == 0) && (((uintptr_t)dst & 15) == 0)) {
        const int4* src4 = (const int4*)src;
        const int4* dst4 = (const int4*)dst;
        for (int i = lo / 4 + t; i < hi / 4; i += THR) {
            int4 dv = dst4[i];
            int4 sv = src4[i];
            unsigned d0 = (unsigned)dv.x, d1 = (unsigned)dv.y;
            unsigned d2 = (unsigned)dv.z, d3 = (unsigned)dv.w;
            uint32_t p0 = atomicAdd(&cur[d0 >> BINBITS], 1u);
            records[p0] = (((unsigned)sv.x) << BINBITS) | (d0 & (BINSZ - 1));
            uint32_t p1 = atomicAdd(&cur[d1 >> BINBITS], 1u);
            records[p1] = (((unsigned)sv.y) << BINBITS) | (d1 & (BINSZ - 1));
            uint32_t p2 = atomicAdd(&cur[d2 >> BINBITS], 1u);
            records[p2] = (((unsigned)sv.z) << BINBITS) | (d2 & (BINSZ - 1));
            uint32_t p3 = atomicAdd(&cur[d3 >> BINBITS], 1u);
            records[p3] = (((unsigned)sv.w) << BINBITS) | (d3 & (BINSZ - 1));
        }
    } else {
        for (int i = lo + t; i < hi; i += THR) {
            unsigned d = (unsigned)dst[i];
            unsigned s = (unsigned)src[i];
            uint32_t slot = atomicAdd(&cur[d >> BINBITS], 1u);
            records[slot] = (s << BINBITS) | (d & (BINSZ - 1));
        }
    }
}

// ---------------- degree / dinv / packed y (whole bin per 1024-thr block) ----

__global__ __launch_bounds__(1024)
void degInline(const uint32_t* __restrict__ records,
               const uint32_t* __restrict__ binStart,
               const float4* __restrict__ x4,
               float* __restrict__ dinv, uint32_t* __restrict__ deg,
               ulonglong2* __restrict__ y4q, int n) {
    __shared__ uint32_t hist[BINSZ];
    int t = threadIdx.x, bin = blockIdx.x;
    if (t < BINSZ) hist[t] = 0u;
    __syncthreads();
    uint32_t lo = binStart[bin], hi = binStart[bin + 1];
    const uint4* rec4 = (const uint4*)records;
    for (uint32_t i = lo / 4 + t; i < hi / 4; i += 1024) {
        uint4 r = rec4[i];
        if (r.x != SENT) atomicAdd(&hist[r.x & (BINSZ - 1)], 1u);
        if (r.y != SENT) atomicAdd(&hist[r.y & (BINSZ - 1)], 1u);
        if (r.z != SENT) atomicAdd(&hist[r.z & (BINSZ - 1)], 1u);
        if (r.w != SENT) atomicAdd(&hist[r.w & (BINSZ - 1)], 1u);
    }
    __syncthreads();
    if (t >= BINSZ) return;
    int node = (bin << BINBITS) + t;
    if (node >= n) return;
    uint32_t c = hist[t];
    float dd = rsqrtf(1.0f + (float)c);
    dinv[node] = dd;
    deg[node] = c;
    float4 xv = x4[node];
    uint32_t q0 = packq(dd * xv.x), q1 = packq(dd * xv.y);
    uint32_t q2 = packq(dd * xv.z), q3 = packq(dd * xv.w);
    ulonglong2 p;
    p.x = ((unsigned long long)q1 << 32) | q0;
    p.y = ((unsigned long long)q3 << 32) | q2;
    y4q[node] = p;
}

// ---------------- layer-1 agg + transform (whole bin per 1024-thr block) ----

__global__ __launch_bounds__(1024)
void aggInline(const uint32_t* __restrict__ records,
               const uint32_t* __restrict__ binStart,
               const ulonglong2* __restrict__ y4q,
               const float* __restrict__ dinv, const uint32_t* __restrict__ deg,
               const float4* __restrict__ x4,
               const float* __restrict__ W1, const float* __restrict__ b1,
               const float* __restrict__ W2,
               float* __restrict__ g, int n) {
    __shared__ unsigned long long acc[2 * BINSZ];
    __shared__ float sW1[128], sb1[32], sW2[32];
    int t = threadIdx.x, bin = blockIdx.x;
    if (t < 2 * BINSZ) acc[t] = 0ull;
    else if (t < 2 * BINSZ + 128) sW1[t - 2 * BINSZ] = W1[t - 2 * BINSZ];
    else if (t < 2 * BINSZ + 160) sb1[t - 2 * BINSZ - 128] = b1[t - 2 * BINSZ - 128];
    else if (t < 2 * BINSZ + 192) sW2[t - 2 * BINSZ - 160] = W2[t - 2 * BINSZ - 160];
    __syncthreads();
    uint32_t base = binStart[bin] / 4, cnt = binStart[bin + 1] / 4;
    const uint4* rec4 = (const uint4*)records;
    for (uint32_t i = base + t; i < cnt; i += 2048) {
        uint4 ra = rec4[i];
        bool hb = (i + 1024) < cnt;
        uint4 rb;
        if (hb) rb = rec4[i + 1024];
        else    rb = make_uint4(SENT, SENT, SENT, SENT);
        // issue all 8 gathers before the atomics (sentinel -> safe idx 0)
        unsigned a0 = (ra.x == SENT) ? 0u : (ra.x >> BINBITS);
        unsigned a1 = (ra.y == SENT) ? 0u : (ra.y >> BINBITS);
        unsigned a2 = (ra.z == SENT) ? 0u : (ra.z >> BINBITS);
        unsigned a3 = (ra.w == SENT) ? 0u : (ra.w >> BINBITS);
        unsigned b0 = (rb.x == SENT) ? 0u : (rb.x >> BINBITS);
        unsigned b1i = (rb.y == SENT) ? 0u : (rb.y >> BINBITS);
        unsigned b2i = (rb.z == SENT) ? 0u : (rb.z >> BINBITS);
        unsigned b3 = (rb.w == SENT) ? 0u : (rb.w >> BINBITS);
        ulonglong2 ya0 = y4q[a0];
        ulonglong2 ya1 = y4q[a1];
        ulonglong2 ya2 = y4q[a2];
        ulonglong2 ya3 = y4q[a3];
        ulonglong2 yb0 = y4q[b0];
        ulonglong2 yb1 = y4q[b1i];
        ulonglong2 yb2 = y4q[b2i];
        ulonglong2 yb3 = y4q[b3];
        if (ra.x != SENT) { unsigned d = ra.x & (BINSZ - 1); atomicAdd(&acc[d], ya0.x); atomicAdd(&acc[BINSZ + d], ya0.y); }
        if (ra.y != SENT) { unsigned d = ra.y & (BINSZ - 1); atomicAdd(&acc[d], ya1.x); atomicAdd(&acc[BINSZ + d], ya1.y); }
        if (ra.z != SENT) { unsigned d = ra.z & (BINSZ - 1); atomicAdd(&acc[d], ya2.x); atomicAdd(&acc[BINSZ + d], ya2.y); }
        if (ra.w != SENT) { unsigned d = ra.w & (BINSZ - 1); atomicAdd(&acc[d], ya3.x); atomicAdd(&acc[BINSZ + d], ya3.y); }
        if (rb.x != SENT) { unsigned d = rb.x & (BINSZ - 1); atomicAdd(&acc[d], yb0.x); atomicAdd(&acc[BINSZ + d], yb0.y); }
        if (rb.y != SENT) { unsigned d = rb.y & (BINSZ - 1); atomicAdd(&acc[d], yb1.x); atomicAdd(&acc[BINSZ + d], yb1.y); }
        if (rb.z != SENT) { unsigned d = rb.z & (BINSZ - 1); atomicAdd(&acc[d], yb2.x); atomicAdd(&acc[BINSZ + d], yb2.y); }
        if (rb.w != SENT) { unsigned d = rb.w & (BINSZ - 1); atomicAdd(&acc[d], yb3.x); atomicAdd(&acc[BINSZ + d], yb3.y); }
    }
    __syncthreads();
    if (t >= BINSZ) return;
    int node = (bin << BINBITS) + t;
    if (node >= n) return;
    unsigned long long P0 = acc[t], P1 = acc[BINSZ + t];
    unsigned long long s0lo = (uint32_t)P0, s0hi = (uint32_t)(P0 >> 32);
    unsigned long long s1lo = (uint32_t)P1, s1hi = (uint32_t)(P1 >> 32);
    // exact de-bias + conversion (R9): split at 2^21 so both halves are exact.
    long long bias = (long long)deg[node] << 25;   // deg * 16 * 2^21
    const float inv = 1.0f / QS;
    long long v0 = (long long)s0lo - bias, v1 = (long long)s0hi - bias;
    long long v2 = (long long)s1lo - bias, v3 = (long long)s1hi - bias;
    float T0 = (float)(v0 >> 21) + (float)(v0 & 0x1FFFFF) * inv;
    float T1 = (float)(v1 >> 21) + (float)(v1 & 0x1FFFFF) * inv;
    float T2 = (float)(v2 >> 21) + (float)(v2 & 0x1FFFFF) * inv;
    float T3 = (float)(v3 >> 21) + (float)(v3 & 0x1FFFFF) * inv;
    float dd = dinv[node];
    float4 xv = x4[node];
    float a0 = dd * (T0 + dd * xv.x), a1 = dd * (T1 + dd * xv.y);
    float a2 = dd * (T2 + dd * xv.z), a3 = dd * (T3 + dd * xv.w);
    float hv = 0.f;
#pragma unroll
    for (int j = 0; j < 32; ++j) {
        float o = fmaf(a0, sW1[j], fmaf(a1, sW1[32 + j],
                  fmaf(a2, sW1[64 + j], fmaf(a3, sW1[96 + j], sb1[j]))));
        hv += fmaxf(o, 0.f) * sW2[j];
    }
    g[node] = dd * hv;
}

// ---------------- layer-2 + sigmoid (whole bin per 1024-thr block) ---------

__global__ __launch_bounds__(1024)
void outInline(const uint32_t* __restrict__ records,
               const uint32_t* __restrict__ binStart,
               const float* __restrict__ g, const float* __restrict__ dinv,
               const float* __restrict__ b2, float* __restrict__ out, int n) {
    __shared__ float accg[BINSZ];
    int t = threadIdx.x, bin = blockIdx.x;
    if (t < BINSZ) accg[t] = 0.f;
    __syncthreads();
    uint32_t lo = binStart[bin], hi = binStart[bin + 1];
    const uint4* rec4 = (const uint4*)records;
    for (uint32_t i = lo / 4 + t; i < hi / 4; i += 1024) {
        uint4 r = rec4[i];
        unsigned s0 = (r.x == SENT) ? 0u : (r.x >> BINBITS);
        unsigned s1 = (r.y == SENT) ? 0u : (r.y >> BINBITS);
        unsigned s2 = (r.z == SENT) ? 0u : (r.z >> BINBITS);
        unsigned s3 = (r.w == SENT) ? 0u : (r.w >> BINBITS);
        float g0 = g[s0], g1 = g[s1], g2 = g[s2], g3 = g[s3];
        if (r.x != SENT) atomicAdd(&accg[r.x & (BINSZ - 1)], g0);
        if (r.y != SENT) atomicAdd(&accg[r.y & (BINSZ - 1)], g1);
        if (r.z != SENT) atomicAdd(&accg[r.z & (BINSZ - 1)], g2);
        if (r.w != SENT) atomicAdd(&accg[r.w & (BINSZ - 1)], g3);
    }
    __syncthreads();
    if (t >= BINSZ) return;
    int node = (bin << BINBITS) + t;
    if (node >= n) return;
    float v = dinv[node] * (accg[t] + g[node]) + b2[0];
    out[node] = 1.0f / (1.0f + expf(-v));
}

// ---------------- launcher ----------------

extern "C" void kernel_launch(void* const* d_in, const int* in_sizes, int n_in,
                              void* d_out, int out_size, void* d_ws, size_t ws_size,
                              hipStream_t stream) {
    const float* x  = (const float*)d_in[0];
    const int*   ei = (const int*)d_in[1];
    const float* W1 = (const float*)d_in[2];
    const float* b1 = (const float*)d_in[3];
    const float* W2 = (const float*)d_in[4];
    const float* b2 = (const float*)d_in[5];
    float* out = (float*)d_out;

    const int n = in_sizes[0] / 4;            // 100000
    const int e = in_sizes[1] / 2;            // 3200000
    const int* src = ei;
    const int* dst = ei + e;

    const int nb = (n + BINSZ - 1) >> BINBITS;   // 391

    size_t recB  = (((size_t)e + 4 * (size_t)nb) * 4 + 15) & ~(size_t)15;  // padded bins
    size_t bcB   = ((size_t)nb * EBC * 4 + 15) & ~(size_t)15;
    size_t bsB   = ((size_t)(2 * nb + 2) * 4 + 15) & ~(size_t)15;
    size_t dinvB = ((size_t)n * 4 + 15) & ~(size_t)15;
    size_t degB  = ((size_t)n * 4 + 15) & ~(size_t)15;
    size_t gB    = ((size_t)n * 4 + 15) & ~(size_t)15;

    char* p = (char*)d_ws;
    uint32_t*   records  = (uint32_t*)p;      p += recB;
    uint32_t*   bc       = (uint32_t*)p;      p += bcB;
    uint32_t*   binStart = (uint32_t*)p;      p += bsB;
    uint32_t*   binSum   = binStart + nb + 1;
    float*      dinv     = (float*)p;         p += dinvB;
    uint32_t*   deg      = (uint32_t*)p;      p += degB;
    float*      gbuf     = (float*)p;         p += gB;
    ulonglong2* y4q      = (ulonglong2*)p;    // n * 16 bytes

    const float4* x4 = (const float4*)x;

    countK<<<EBC, THR, 0, stream>>>(dst, bc, e, nb);
    scan1K<<<nb, EBC, 0, stream>>>(bc, binSum);
    scan2K<<<1, 512, 0, stream>>>(binSum, binStart, records, nb);
    fillK <<<EBC, THR, 0, stream>>>(src, dst, bc, binStart, records, e, nb);

    degInline<<<nb, 1024, 0, stream>>>(records, binStart, x4, dinv, deg, y4q, n);
    aggInline<<<nb, 1024, 0, stream>>>(records, binStart, y4q, dinv, deg, x4,
                                       W1, b1, W2, gbuf, n);
    outInline<<<nb, 1024, 0, stream>>>(records, binStart, gbuf, dinv, b2, out, n);
}